// Round 1
// 332.627 us; speedup vs baseline: 1.0223x; 1.0223x over previous
//
#include <hip/hip_runtime.h>
#include <hip/hip_bf16.h>
#include <math.h>
#include <stdint.h>

// ---------------------------------------------------------------------------
// Attention_17231408791684: x->QKV (bias) -> RoPE -> sliding-window(128)
// causal attention w/ sinks -> O-proj (bias).  f32 in/out, bf16 compute.
// Round 8: attention restructured. One block = (64-query tile, kv-head
// group): K/V staged+rope'd ONCE per group of 8 heads (was 8x redundant).
// 8 waves, wave = 1 head x 64 rows. Swapped QK^T (mfma(K,Q)) puts each
// q-row's scores lane-local -> 2-step softmax reduce, sink factor folded
// into P, P redistributed to PV A-frags in-register via pack+shfl (no P
// LDS, one barrier total). Vt stride 200 (2-way, was 4-way conflict).
// Grid 256 = 1 block/CU exactly. Sliding-window frag skip: 9/12 QK frags,
// 5/6 PV chunks per f-step.
// ---------------------------------------------------------------------------

typedef __bf16 bf16x8 __attribute__((ext_vector_type(8)));
typedef float  f32x4  __attribute__((ext_vector_type(4)));
typedef uint32_t u32x4 __attribute__((ext_vector_type(4)));

#define MFMA_BF16(a,b,c) __builtin_amdgcn_mfma_f32_16x16x32_bf16((a),(b),(c),0,0,0)

// workspace element offsets (bf16 elements)
#define XB   0L
#define WQB  5898240L
#define WKB  17694720L
#define WVB  19169280L
#define WOB  20643840L
#define QB   32440320L
#define KB   40828928L
#define VB   41877504L

__device__ __forceinline__ void gld_lds16(const void* g, void* l) {
    __builtin_amdgcn_global_load_lds(
        (__attribute__((address_space(1))) void*)(g),
        (__attribute__((address_space(3))) void*)(l), 16, 0, 0);
}

__device__ __forceinline__ bf16x8 ld8f(const float* p) {
    f32x4 a = *(const f32x4*)p;
    f32x4 b = *(const f32x4*)(p + 4);
    bf16x8 r;
#pragma unroll
    for (int t = 0; t < 4; t++) { r[t] = (__bf16)a[t]; r[t + 4] = (__bf16)b[t]; }
    return r;
}

__device__ __forceinline__ uint32_t pack2(float a, float b) {
    __bf16 x = (__bf16)a, y = (__bf16)b;
    return (uint32_t)__builtin_bit_cast(unsigned short, x)
         | ((uint32_t)__builtin_bit_cast(unsigned short, y) << 16);
}

// ---------------------------------------------------------------------------
// f32 -> bf16 conversion of {x, wq, wk, wv, wo}; 8 elems/thread, 15840x256.
// ---------------------------------------------------------------------------
__global__ __launch_bounds__(256) void convert_kernel(
    const float* __restrict__ x,  const float* __restrict__ wq,
    const float* __restrict__ wk, const float* __restrict__ wv,
    const float* __restrict__ wo, __bf16* __restrict__ dst)
{
    long e = ((long)blockIdx.x * 256 + threadIdx.x) * 8;
    const float* src; long off;
    if      (e <  WQB) { src = x;  off = e; }
    else if (e <  WKB) { src = wq; off = e - WQB; }
    else if (e <  WVB) { src = wk; off = e - WKB; }
    else if (e <  WOB) { src = wv; off = e - WVB; }
    else               { src = wo; off = e - WOB; }
    *(bf16x8*)(dst + e) = ld8f(src + off);
}

// ---------------------------------------------------------------------------
// NT GEMM, BK=64, k in [kBeg,kEnd). 128x128 tile, 256 thr (2x2 waves of
// 64x64). LDS [2][128][32]/operand. bias==nullptr -> none.
// ---------------------------------------------------------------------------
__device__ __forceinline__ void gemm_block64(
    const __bf16* __restrict__ A, const __bf16* __restrict__ W,
    const float* __restrict__ bias, __bf16* __restrict__ C,
    int N, int Ks, int kBeg, int kEnd, int m0, int n0,
    __bf16* As, __bf16* Bs)
{
    const int tid  = threadIdx.x;
    const int lane = tid & 63;
    const int wv   = tid >> 6;
    const int wm   = (wv >> 1) * 64;
    const int wn   = (wv & 1) * 64;
    const int quad = lane >> 4;
    const int c    = lane & 15;

    const int srow = tid >> 2;          // 0..63
    const int scol = (tid & 3) * 8;     // 0,8,16,24

    int br0 = n0 + srow;      if (br0 > N - 1) br0 = N - 1;
    int br1 = n0 + 64 + srow; if (br1 > N - 1) br1 = N - 1;
    const __bf16* pa0 = A + (size_t)(m0 + srow) * Ks + scol;
    const __bf16* pa1 = A + (size_t)(m0 + 64 + srow) * Ks + scol;
    const __bf16* pb0 = W + (size_t)br0 * Ks + scol;
    const __bf16* pb1 = W + (size_t)br1 * Ks + scol;

    f32x4 acc[4][4];
#pragma unroll
    for (int i = 0; i < 4; i++)
#pragma unroll
        for (int j = 0; j < 4; j++) acc[i][j] = (f32x4){0.f, 0.f, 0.f, 0.f};

    for (int kk = kBeg; kk < kEnd; kk += 64) {
        gld_lds16(pa0 + kk,      As + tid * 8);
        gld_lds16(pa1 + kk,      As + 2048 + tid * 8);
        gld_lds16(pa0 + kk + 32, As + 4096 + tid * 8);
        gld_lds16(pa1 + kk + 32, As + 6144 + tid * 8);
        gld_lds16(pb0 + kk,      Bs + tid * 8);
        gld_lds16(pb1 + kk,      Bs + 2048 + tid * 8);
        gld_lds16(pb0 + kk + 32, Bs + 4096 + tid * 8);
        gld_lds16(pb1 + kk + 32, Bs + 6144 + tid * 8);
        __syncthreads();
        for (int kt = 0; kt < 2; kt++) {
            bf16x8 af[4], bfv[4];
#pragma unroll
            for (int i = 0; i < 4; i++)
                af[i] = *(const bf16x8*)&As[kt * 4096 + (wm + i * 16 + c) * 32 + quad * 8];
#pragma unroll
            for (int j = 0; j < 4; j++)
                bfv[j] = *(const bf16x8*)&Bs[kt * 4096 + (wn + j * 16 + c) * 32 + quad * 8];
#pragma unroll
            for (int i = 0; i < 4; i++)
#pragma unroll
                for (int j = 0; j < 4; j++)
                    acc[i][j] = MFMA_BF16(af[i], bfv[j], acc[i][j]);
        }
        __syncthreads();
    }

#pragma unroll
    for (int j = 0; j < 4; j++) {
        int col = n0 + wn + j * 16 + c;
        if (col >= N) continue;
        float bv = bias ? bias[col] : 0.0f;
#pragma unroll
        for (int i = 0; i < 4; i++) {
            int row = m0 + wm + i * 16 + quad * 4;
#pragma unroll
            for (int r = 0; r < 4; r++)
                C[(size_t)(row + r) * N + col] = (__bf16)(acc[i][j][r] + bv);
        }
    }
}

// Fused QKV, whole-K: grid (16,40); by<32 -> q, by<36 -> k, else v.
__global__ __launch_bounds__(256, 3) void qkv_kernel(
    const __bf16* __restrict__ x,
    const __bf16* __restrict__ wq, const float* __restrict__ bq,
    const __bf16* __restrict__ wk, const float* __restrict__ bk,
    const __bf16* __restrict__ wv, const float* __restrict__ bv,
    __bf16* __restrict__ qo, __bf16* __restrict__ ko, __bf16* __restrict__ vo)
{
    __shared__ __align__(16) __bf16 As[8192], Bs[8192];
    const int by = blockIdx.y;
    const __bf16 *W; const float* bias; __bf16* C; int N, n0;
    if (by < 32)      { W = wq; bias = bq; C = qo; N = 4096; n0 = by * 128; }
    else if (by < 36) { W = wk; bias = bk; C = ko; N = 512;  n0 = (by - 32) * 128; }
    else              { W = wv; bias = bv; C = vo; N = 512;  n0 = (by - 36) * 128; }
    gemm_block64(x, W, bias, C, N, 2880, 0, 2880, blockIdx.x * 128, n0, As, Bs);
}

// O-proj split-K=2 partials: grid (16,23,2); k halves of 4096.
__global__ __launch_bounds__(256, 3) void oproj_kernel(
    const __bf16* __restrict__ a, const __bf16* __restrict__ w,
    __bf16* __restrict__ p0, __bf16* __restrict__ p1)
{
    __shared__ __align__(16) __bf16 As[8192], Bs[8192];
    const int z = blockIdx.z;
    __bf16* C = z ? p1 : p0;
    gemm_block64(a, w, nullptr, C, 2880, 4096, z * 2048, (z + 1) * 2048,
                 blockIdx.x * 128, blockIdx.y * 128, As, Bs);
}

// out[e] = p0[e] + p1[e] + bias[col]; 8 elems/thread, grid 2880x256 exact.
__global__ __launch_bounds__(256) void reduce_kernel(
    const __bf16* __restrict__ p0, const __bf16* __restrict__ p1,
    const float* __restrict__ bo, float* __restrict__ out)
{
    long e = ((long)blockIdx.x * 256 + threadIdx.x) * 8;
    int col = (int)(e % 2880L);          // 2880 % 8 == 0: no row crossing
    bf16x8 a = *(const bf16x8*)(p0 + e);
    bf16x8 b = *(const bf16x8*)(p1 + e);
    f32x4 o0, o1;
#pragma unroll
    for (int t = 0; t < 4; t++) {
        o0[t] = (float)a[t]     + (float)b[t]     + bo[col + t];
        o1[t] = (float)a[4 + t] + (float)b[4 + t] + bo[col + 4 + t];
    }
    *(f32x4*)(out + e)     = o0;
    *(f32x4*)(out + e + 4) = o1;
}

// ---------------------------------------------------------------------------
// Attention, fused RoPE, in-place on q. Grid (32 q-tiles, 8 kv-heads),
// 512 threads = 8 waves; wave w = head kvh*8+w, all 64 rows of the tile.
// K (rope'd) and V^T staged ONCE per block (shared by 8 heads).
// Swapped QK^T: acc = mfma(K-frag, Q-frag) -> lane (quad,c) holds
// S[key = j*16+quad*4+r][qrow = c]: softmax reduce = shfl_xor(16,32) over
// the 4-lane column group; sigmoid(lse-sink)/rowsum folded into P; P
// redistributed to PV A-fragment layout in-register (pack2 + 8 shfl per
// 32-key chunk, traffic stays inside {c,c+16,c+32,c+48}).
// Window skip: per 16-row f-step only key-frags [f,f+8] and PV chunks
// [f>>1, f>>1+4] intersect the 128-sliding window; rest are hard zeros.
// LDS: Ks[192][72] (2-way bank), Vt[64][200] (2-way bank) = 53KB.
// ---------------------------------------------------------------------------
__global__ __launch_bounds__(512) void attn_kernel(
    __bf16* __restrict__ q, const __bf16* __restrict__ k,
    const __bf16* __restrict__ v, const float* __restrict__ sinks,
    const float* __restrict__ rope)
{
    __shared__ __align__(16) __bf16 Ks[192 * 72];
    __shared__ __align__(16) __bf16 Vt[64 * 200];

    const int tid = threadIdx.x, lane = tid & 63, w = tid >> 6;
    const int quad = lane >> 4, c = lane & 15;
    const int i0  = blockIdx.x * 64;
    const int kvh = blockIdx.y;
    const int h   = kvh * 8 + w;
    const int k0  = i0 - 128;
    const float scale = 0.16832169878499658f;   // (0.1*ln32+1)/sqrt(64)

    // ---- stage K with rope: 192 rows x 64 dims, 768 units of 16 elems
#pragma unroll
    for (int it = 0; it < 2; it++) {
        int unit = it * 512 + tid;
        if (unit < 768) {
            int krow = unit >> 2;
            int kdg  = (unit & 3) * 8;
            int j = k0 + krow; if (j < 0) j = 0;
            const __bf16* gp = k + (size_t)j * 512 + kvh * 64 + kdg;
            bf16x8 x1 = *(const bf16x8*)(gp);
            bf16x8 x2 = *(const bf16x8*)(gp + 32);
            const float* rc = rope + (size_t)j * 128 + kdg;
            bf16x8 o1, o2;
#pragma unroll
            for (int t = 0; t < 8; t++) {
                float cc = rc[t], si = rc[64 + t];
                float a = (float)x1[t], b = (float)x2[t];
                o1[t] = (__bf16)(a * cc - b * si);
                o2[t] = (__bf16)(b * cc + a * si);
            }
            *(bf16x8*)&Ks[krow * 72 + kdg]      = o1;
            *(bf16x8*)&Ks[krow * 72 + kdg + 32] = o2;
        }
    }

    // ---- stage V transposed: Vt[d][s]  (s = staged key index)
    {
        const int vrow = tid & 63;
        const int d0   = (tid >> 6) * 8;
#pragma unroll
        for (int it = 0; it < 3; it++) {
            int s = it * 64 + vrow;
            int j = k0 + s; if (j < 0) j = 0;
            bf16x8 t = *(const bf16x8*)(v + (size_t)j * 512 + kvh * 64 + d0);
#pragma unroll
            for (int u = 0; u < 8; u++) Vt[(d0 + u) * 200 + s] = t[u];
        }
    }

    // ---- Q fragments (B-operand layout: row=c), rope + scale folded in
    bf16x8 qf[4][2];
#pragma unroll
    for (int f = 0; f < 4; f++) {
        const int row = i0 + f * 16 + c;
        const __bf16* gp = q + (size_t)row * 4096 + h * 64 + quad * 8;
        bf16x8 x1 = *(const bf16x8*)(gp);
        bf16x8 x2 = *(const bf16x8*)(gp + 32);
        const float* rc = rope + (size_t)row * 128 + quad * 8;
        bf16x8 o1, o2;
#pragma unroll
        for (int t = 0; t < 8; t++) {
            float cc = rc[t] * scale, si = rc[64 + t] * scale;
            float a = (float)x1[t], b = (float)x2[t];
            o1[t] = (__bf16)(a * cc - b * si);
            o2[t] = (__bf16)(b * cc + a * si);
        }
        qf[f][0] = o1; qf[f][1] = o2;
    }

    __syncthreads();

    const float sk   = sinks[h];
    const int laneA  = ((quad & 1) << 5) + c;   // owner quad (quad&1)*2
    const int laneB  = laneA + 16;              // owner quad (quad&1)*2+1
    const bool hiSel = (quad >> 1) != 0;        // needs j = 2kt+1
    const int db     = 128 + c - quad * 4;      // ig - jg, jj/r part removed

#pragma unroll
    for (int f = 0; f < 4; f++) {
        // ---- swapped QK^T: acc9[jj] = S[key (f+jj)*16+quad*4+r][q = c]
        f32x4 acc9[9];
#pragma unroll
        for (int jj = 0; jj < 9; jj++) acc9[jj] = (f32x4){0.f, 0.f, 0.f, 0.f};
        __builtin_amdgcn_s_setprio(1);
#pragma unroll
        for (int jj = 0; jj < 9; jj++) {
            const int j = f + jj;
#pragma unroll
            for (int kt = 0; kt < 2; kt++) {
                bf16x8 kf = *(const bf16x8*)&Ks[(j * 16 + c) * 72 + kt * 32 + quad * 8];
                acc9[jj] = MFMA_BF16(kf, qf[f][kt], acc9[jj]);
            }
        }
        __builtin_amdgcn_s_setprio(0);

        // ---- mask + row max (d = ig - jg; valid iff 0<=d<128 && jg>=0)
        const int jgb = k0 + f * 16 + quad * 4;
        float rmax = -3.0e4f;
#pragma unroll
        for (int jj = 0; jj < 9; jj++)
#pragma unroll
            for (int r = 0; r < 4; r++) {
                int d  = db  - jj * 16 - r;
                int jg = jgb + jj * 16 + r;
                bool ok = ((unsigned)d < 128u) && (jg >= 0);
                float vv = ok ? acc9[jj][r] : -3.0e4f;
                acc9[jj][r] = vv;
                rmax = fmaxf(rmax, vv);
            }
        rmax = fmaxf(rmax, __shfl_xor(rmax, 16));
        rmax = fmaxf(rmax, __shfl_xor(rmax, 32));

        float rs = 0.f;
#pragma unroll
        for (int jj = 0; jj < 9; jj++)
#pragma unroll
            for (int r = 0; r < 4; r++) {
                float e = __expf(acc9[jj][r] - rmax);
                acc9[jj][r] = e;
                rs += e;
            }
        rs += __shfl_xor(rs, 16);
        rs += __shfl_xor(rs, 32);

        // rowfac = sigmoid(lse - sink) / rowsum, folded into P
        float s   = fmaxf(rs, 1e-20f);
        float lse = rmax + __logf(s);
        float fac = 1.f / ((1.f + __expf(sk - lse)) * s);

        // ---- pack P*fac to bf16 pairs; uncovered frags stay exactly 0
        uint32_t pk[24];
#pragma unroll
        for (int t = 0; t < 24; t++) pk[t] = 0;
#pragma unroll
        for (int jj = 0; jj < 9; jj++) {
            const int j = f + jj;
            pk[2 * j]     = pack2(acc9[jj][0] * fac, acc9[jj][1] * fac);
            pk[2 * j + 1] = pack2(acc9[jj][2] * fac, acc9[jj][3] * fac);
        }

        // ---- PV: rebuild A-frags via shfl (within {c,c+16,c+32,c+48})
        f32x4 acc2[4];
#pragma unroll
        for (int jd = 0; jd < 4; jd++) acc2[jd] = (f32x4){0.f, 0.f, 0.f, 0.f};
        const int kt0 = f >> 1;
#pragma unroll
        for (int kk = 0; kk < 5; kk++) {
            const int kt = kt0 + kk;
            uint32_t l0  = (uint32_t)__shfl((int)pk[4 * kt],     laneA);
            uint32_t h0  = (uint32_t)__shfl((int)pk[4 * kt + 1], laneA);
            uint32_t l0b = (uint32_t)__shfl((int)pk[4 * kt],     laneB);
            uint32_t h0b = (uint32_t)__shfl((int)pk[4 * kt + 1], laneB);
            uint32_t l1  = (uint32_t)__shfl((int)pk[4 * kt + 2], laneA);
            uint32_t h1  = (uint32_t)__shfl((int)pk[4 * kt + 3], laneA);
            uint32_t l1b = (uint32_t)__shfl((int)pk[4 * kt + 2], laneB);
            uint32_t h1b = (uint32_t)__shfl((int)pk[4 * kt + 3], laneB);
            u32x4 wv = { hiSel ? l1  : l0,  hiSel ? h1  : h0,
                         hiSel ? l1b : l0b, hiSel ? h1b : h0b };
            bf16x8 pa = __builtin_bit_cast(bf16x8, wv);
            __builtin_amdgcn_s_setprio(1);
#pragma unroll
            for (int jd = 0; jd < 4; jd++) {
                bf16x8 bv = *(const bf16x8*)&Vt[(jd * 16 + c) * 200 + kt * 32 + quad * 8];
                acc2[jd] = MFMA_BF16(pa, bv, acc2[jd]);
            }
            __builtin_amdgcn_s_setprio(0);
        }

        // ---- store O rows of this f (sink factor already folded into P)
#pragma unroll
        for (int jd = 0; jd < 4; jd++)
#pragma unroll
            for (int r = 0; r < 4; r++)
                q[(size_t)(i0 + f * 16 + quad * 4 + r) * 4096 + h * 64 + jd * 16 + c]
                    = (__bf16)acc2[jd][r];
    }
}

// ---------------------------------------------------------------------------
extern "C" void kernel_launch(void* const* d_in, const int* in_sizes, int n_in,
                              void* d_out, int out_size, void* d_ws, size_t ws_size,
                              hipStream_t stream) {
    const float* x    = (const float*)d_in[0];
    const float* rope = (const float*)d_in[1];
    const float* wq   = (const float*)d_in[2];
    const float* bq   = (const float*)d_in[3];
    const float* wk   = (const float*)d_in[4];
    const float* bk   = (const float*)d_in[5];
    const float* wv   = (const float*)d_in[6];
    const float* bv   = (const float*)d_in[7];
    const float* wo   = (const float*)d_in[8];
    const float* bo   = (const float*)d_in[9];
    const float* sk   = (const float*)d_in[10];
    float* out = (float*)d_out;

    __bf16* wsb = (__bf16*)d_ws;
    __bf16* xb  = wsb + XB;
    __bf16* wqb = wsb + WQB;
    __bf16* wkb = wsb + WKB;
    __bf16* wvb = wsb + WVB;
    __bf16* wob = wsb + WOB;
    __bf16* qb  = wsb + QB;
    __bf16* kb  = wsb + KB;
    __bf16* vb  = wsb + VB;
    __bf16* po0 = wsb + 0L;            // oproj partials overlay dead xb/wqb
    __bf16* po1 = wsb + 5898240L;

    convert_kernel<<<15840, 256, 0, stream>>>(x, wq, wk, wv, wo, xb);
    qkv_kernel<<<dim3(16, 40), 256, 0, stream>>>(xb, wqb, bq, wkb, bk, wvb, bv,
                                                 qb, kb, vb);
    attn_kernel<<<dim3(32, 8), 512, 0, stream>>>(qb, kb, vb, sk, rope);
    oproj_kernel<<<dim3(16, 23, 2), 256, 0, stream>>>(qb, wob, po0, po1);
    reduce_kernel<<<2880, 256, 0, stream>>>(po0, po1, bo, out);
}

// Round 2
// 330.079 us; speedup vs baseline: 1.0302x; 1.0077x over previous
//
#include <hip/hip_runtime.h>
#include <hip/hip_bf16.h>
#include <math.h>
#include <stdint.h>

// ---------------------------------------------------------------------------
// Attention_17231408791684: x->QKV (bias) -> RoPE -> sliding-window(128)
// causal attention w/ sinks -> O-proj (bias).  f32 in/out, bf16 compute.
// Round 9: (a) attn f-loop -> template<int F> explicit steps: guarantees
// static indexing of qf/acc9/pk (rule-#20 scratch-spill insurance; pk
// shrunk 24->20 words via static window). (b) XCD-aware bijective block
// swizzle on qkv (640=8x80) and oproj (368=8x46): per-XCD contiguous
// n-tile chunks -> W panels L2-resident.
// ---------------------------------------------------------------------------

typedef __bf16 bf16x8 __attribute__((ext_vector_type(8)));
typedef float  f32x4  __attribute__((ext_vector_type(4)));
typedef uint32_t u32x4 __attribute__((ext_vector_type(4)));

#define MFMA_BF16(a,b,c) __builtin_amdgcn_mfma_f32_16x16x32_bf16((a),(b),(c),0,0,0)

// workspace element offsets (bf16 elements)
#define XB   0L
#define WQB  5898240L
#define WKB  17694720L
#define WVB  19169280L
#define WOB  20643840L
#define QB   32440320L
#define KB   40828928L
#define VB   41877504L

__device__ __forceinline__ void gld_lds16(const void* g, void* l) {
    __builtin_amdgcn_global_load_lds(
        (__attribute__((address_space(1))) void*)(g),
        (__attribute__((address_space(3))) void*)(l), 16, 0, 0);
}

__device__ __forceinline__ bf16x8 ld8f(const float* p) {
    f32x4 a = *(const f32x4*)p;
    f32x4 b = *(const f32x4*)(p + 4);
    bf16x8 r;
#pragma unroll
    for (int t = 0; t < 4; t++) { r[t] = (__bf16)a[t]; r[t + 4] = (__bf16)b[t]; }
    return r;
}

__device__ __forceinline__ uint32_t pack2(float a, float b) {
    __bf16 x = (__bf16)a, y = (__bf16)b;
    return (uint32_t)__builtin_bit_cast(unsigned short, x)
         | ((uint32_t)__builtin_bit_cast(unsigned short, y) << 16);
}

// ---------------------------------------------------------------------------
// f32 -> bf16 conversion of {x, wq, wk, wv, wo}; 8 elems/thread, 15840x256.
// ---------------------------------------------------------------------------
__global__ __launch_bounds__(256) void convert_kernel(
    const float* __restrict__ x,  const float* __restrict__ wq,
    const float* __restrict__ wk, const float* __restrict__ wv,
    const float* __restrict__ wo, __bf16* __restrict__ dst)
{
    long e = ((long)blockIdx.x * 256 + threadIdx.x) * 8;
    const float* src; long off;
    if      (e <  WQB) { src = x;  off = e; }
    else if (e <  WKB) { src = wq; off = e - WQB; }
    else if (e <  WVB) { src = wk; off = e - WKB; }
    else if (e <  WOB) { src = wv; off = e - WVB; }
    else               { src = wo; off = e - WOB; }
    *(bf16x8*)(dst + e) = ld8f(src + off);
}

// ---------------------------------------------------------------------------
// NT GEMM, BK=64, k in [kBeg,kEnd). 128x128 tile, 256 thr (2x2 waves of
// 64x64). LDS [2][128][32]/operand. bias==nullptr -> none.
// ---------------------------------------------------------------------------
__device__ __forceinline__ void gemm_block64(
    const __bf16* __restrict__ A, const __bf16* __restrict__ W,
    const float* __restrict__ bias, __bf16* __restrict__ C,
    int N, int Ks, int kBeg, int kEnd, int m0, int n0,
    __bf16* As, __bf16* Bs)
{
    const int tid  = threadIdx.x;
    const int lane = tid & 63;
    const int wv   = tid >> 6;
    const int wm   = (wv >> 1) * 64;
    const int wn   = (wv & 1) * 64;
    const int quad = lane >> 4;
    const int c    = lane & 15;

    const int srow = tid >> 2;          // 0..63
    const int scol = (tid & 3) * 8;     // 0,8,16,24

    int br0 = n0 + srow;      if (br0 > N - 1) br0 = N - 1;
    int br1 = n0 + 64 + srow; if (br1 > N - 1) br1 = N - 1;
    const __bf16* pa0 = A + (size_t)(m0 + srow) * Ks + scol;
    const __bf16* pa1 = A + (size_t)(m0 + 64 + srow) * Ks + scol;
    const __bf16* pb0 = W + (size_t)br0 * Ks + scol;
    const __bf16* pb1 = W + (size_t)br1 * Ks + scol;

    f32x4 acc[4][4];
#pragma unroll
    for (int i = 0; i < 4; i++)
#pragma unroll
        for (int j = 0; j < 4; j++) acc[i][j] = (f32x4){0.f, 0.f, 0.f, 0.f};

    for (int kk = kBeg; kk < kEnd; kk += 64) {
        gld_lds16(pa0 + kk,      As + tid * 8);
        gld_lds16(pa1 + kk,      As + 2048 + tid * 8);
        gld_lds16(pa0 + kk + 32, As + 4096 + tid * 8);
        gld_lds16(pa1 + kk + 32, As + 6144 + tid * 8);
        gld_lds16(pb0 + kk,      Bs + tid * 8);
        gld_lds16(pb1 + kk,      Bs + 2048 + tid * 8);
        gld_lds16(pb0 + kk + 32, Bs + 4096 + tid * 8);
        gld_lds16(pb1 + kk + 32, Bs + 6144 + tid * 8);
        __syncthreads();
        for (int kt = 0; kt < 2; kt++) {
            bf16x8 af[4], bfv[4];
#pragma unroll
            for (int i = 0; i < 4; i++)
                af[i] = *(const bf16x8*)&As[kt * 4096 + (wm + i * 16 + c) * 32 + quad * 8];
#pragma unroll
            for (int j = 0; j < 4; j++)
                bfv[j] = *(const bf16x8*)&Bs[kt * 4096 + (wn + j * 16 + c) * 32 + quad * 8];
#pragma unroll
            for (int i = 0; i < 4; i++)
#pragma unroll
                for (int j = 0; j < 4; j++)
                    acc[i][j] = MFMA_BF16(af[i], bfv[j], acc[i][j]);
        }
        __syncthreads();
    }

#pragma unroll
    for (int j = 0; j < 4; j++) {
        int col = n0 + wn + j * 16 + c;
        if (col >= N) continue;
        float bv = bias ? bias[col] : 0.0f;
#pragma unroll
        for (int i = 0; i < 4; i++) {
            int row = m0 + wm + i * 16 + quad * 4;
#pragma unroll
            for (int r = 0; r < 4; r++)
                C[(size_t)(row + r) * N + col] = (__bf16)(acc[i][j][r] + bv);
        }
    }
}

// Fused QKV, whole-K: grid (16,40); by<32 -> q, by<36 -> k, else v.
// XCD swizzle: 640 blocks = 8 XCDs x 80; each XCD gets 5 contiguous
// n-tiles (W panels ~L2-resident) x all 16 m-tiles.
__global__ __launch_bounds__(256, 3) void qkv_kernel(
    const __bf16* __restrict__ x,
    const __bf16* __restrict__ wq, const float* __restrict__ bq,
    const __bf16* __restrict__ wk, const float* __restrict__ bk,
    const __bf16* __restrict__ wv, const float* __restrict__ bv,
    __bf16* __restrict__ qo, __bf16* __restrict__ ko, __bf16* __restrict__ vo)
{
    __shared__ __align__(16) __bf16 As[8192], Bs[8192];
    const int orig = blockIdx.y * 16 + blockIdx.x;
    const int wg   = (orig & 7) * 80 + (orig >> 3);
    const int bx   = wg & 15;
    const int by   = wg >> 4;
    const __bf16 *W; const float* bias; __bf16* C; int N, n0;
    if (by < 32)      { W = wq; bias = bq; C = qo; N = 4096; n0 = by * 128; }
    else if (by < 36) { W = wk; bias = bk; C = ko; N = 512;  n0 = (by - 32) * 128; }
    else              { W = wv; bias = bv; C = vo; N = 512;  n0 = (by - 36) * 128; }
    gemm_block64(x, W, bias, C, N, 2880, 0, 2880, bx * 128, n0, As, Bs);
}

// O-proj split-K=2 partials: grid (16,23,2); k halves of 4096.
// XCD swizzle per z-slice: 368 = 8 x 46.
__global__ __launch_bounds__(256, 3) void oproj_kernel(
    const __bf16* __restrict__ a, const __bf16* __restrict__ w,
    __bf16* __restrict__ p0, __bf16* __restrict__ p1)
{
    __shared__ __align__(16) __bf16 As[8192], Bs[8192];
    const int z = blockIdx.z;
    __bf16* C = z ? p1 : p0;
    const int orig = blockIdx.y * 16 + blockIdx.x;
    const int wg   = (orig & 7) * 46 + (orig >> 3);
    const int bx   = wg & 15;
    const int by   = wg >> 4;
    gemm_block64(a, w, nullptr, C, 2880, 4096, z * 2048, (z + 1) * 2048,
                 bx * 128, by * 128, As, Bs);
}

// out[e] = p0[e] + p1[e] + bias[col]; 8 elems/thread, grid 2880x256 exact.
__global__ __launch_bounds__(256) void reduce_kernel(
    const __bf16* __restrict__ p0, const __bf16* __restrict__ p1,
    const float* __restrict__ bo, float* __restrict__ out)
{
    long e = ((long)blockIdx.x * 256 + threadIdx.x) * 8;
    int col = (int)(e % 2880L);          // 2880 % 8 == 0: no row crossing
    bf16x8 a = *(const bf16x8*)(p0 + e);
    bf16x8 b = *(const bf16x8*)(p1 + e);
    f32x4 o0, o1;
#pragma unroll
    for (int t = 0; t < 4; t++) {
        o0[t] = (float)a[t]     + (float)b[t]     + bo[col + t];
        o1[t] = (float)a[4 + t] + (float)b[4 + t] + bo[col + 4 + t];
    }
    *(f32x4*)(out + e)     = o0;
    *(f32x4*)(out + e + 4) = o1;
}

// ---------------------------------------------------------------------------
// Attention f-step, F = 0..3 compile-time. All array indices static.
// acc9[jj] = S[key (F+jj)*16+quad*4+r][q = c] (swapped QK^T), softmax in
// lane-column group {c,c+16,c+32,c+48}, sink factor folded into P, P
// redistributed to PV A-frags via pack2 + shfl.
// pk window: global words [4*(F>>1), 4*(F>>1)+19]; writes land at local
// (F even ? 2*jj : 2*jj+2); the 2 pad words are exactly the masked zeros.
// ---------------------------------------------------------------------------
template<int F>
__device__ __forceinline__ void attn_f_step(
    const __bf16* __restrict__ Ks, const __bf16* __restrict__ Vt,
    __bf16* __restrict__ q, bf16x8 qf0, bf16x8 qf1,
    int i0, int h, int k0, float sk,
    int c, int quad, int laneA, int laneB, bool hiSel, int db)
{
    // ---- swapped QK^T
    f32x4 acc9[9];
#pragma unroll
    for (int jj = 0; jj < 9; jj++) acc9[jj] = (f32x4){0.f, 0.f, 0.f, 0.f};
    __builtin_amdgcn_s_setprio(1);
#pragma unroll
    for (int jj = 0; jj < 9; jj++) {
        const int j = F + jj;
        bf16x8 kf0 = *(const bf16x8*)&Ks[(j * 16 + c) * 72 + quad * 8];
        bf16x8 kf1 = *(const bf16x8*)&Ks[(j * 16 + c) * 72 + 32 + quad * 8];
        acc9[jj] = MFMA_BF16(kf0, qf0, acc9[jj]);
        acc9[jj] = MFMA_BF16(kf1, qf1, acc9[jj]);
    }
    __builtin_amdgcn_s_setprio(0);

    // ---- mask + row max (d = ig - jg; valid iff 0<=d<128 && jg>=0)
    const int jgb = k0 + F * 16 + quad * 4;
    float rmax = -3.0e4f;
#pragma unroll
    for (int jj = 0; jj < 9; jj++)
#pragma unroll
        for (int r = 0; r < 4; r++) {
            int d  = db  - jj * 16 - r;
            int jg = jgb + jj * 16 + r;
            bool ok = ((unsigned)d < 128u) && (jg >= 0);
            float vv = ok ? acc9[jj][r] : -3.0e4f;
            acc9[jj][r] = vv;
            rmax = fmaxf(rmax, vv);
        }
    rmax = fmaxf(rmax, __shfl_xor(rmax, 16));
    rmax = fmaxf(rmax, __shfl_xor(rmax, 32));

    float rs = 0.f;
#pragma unroll
    for (int jj = 0; jj < 9; jj++)
#pragma unroll
        for (int r = 0; r < 4; r++) {
            float e = __expf(acc9[jj][r] - rmax);
            acc9[jj][r] = e;
            rs += e;
        }
    rs += __shfl_xor(rs, 16);
    rs += __shfl_xor(rs, 32);

    // rowfac = sigmoid(lse - sink) / rowsum, folded into P
    float s   = fmaxf(rs, 1e-20f);
    float lse = rmax + __logf(s);
    float fac = 1.f / ((1.f + __expf(sk - lse)) * s);

    // ---- pack P*fac to bf16 pairs into static 20-word window
    uint32_t pk[20];
#pragma unroll
    for (int t = 0; t < 20; t++) pk[t] = 0;
#pragma unroll
    for (int jj = 0; jj < 9; jj++) {
        const int li = (F & 1) ? (2 * jj + 2) : (2 * jj);
        pk[li]     = pack2(acc9[jj][0] * fac, acc9[jj][1] * fac);
        pk[li + 1] = pack2(acc9[jj][2] * fac, acc9[jj][3] * fac);
    }

    // ---- PV: rebuild A-frags via shfl (within {c,c+16,c+32,c+48})
    f32x4 acc2[4];
#pragma unroll
    for (int jd = 0; jd < 4; jd++) acc2[jd] = (f32x4){0.f, 0.f, 0.f, 0.f};
#pragma unroll
    for (int kk = 0; kk < 5; kk++) {
        const int kt = (F >> 1) + kk;        // Vt chunk (global)
        uint32_t l0  = (uint32_t)__shfl((int)pk[4 * kk],     laneA);
        uint32_t h0  = (uint32_t)__shfl((int)pk[4 * kk + 1], laneA);
        uint32_t l0b = (uint32_t)__shfl((int)pk[4 * kk],     laneB);
        uint32_t h0b = (uint32_t)__shfl((int)pk[4 * kk + 1], laneB);
        uint32_t l1  = (uint32_t)__shfl((int)pk[4 * kk + 2], laneA);
        uint32_t h1  = (uint32_t)__shfl((int)pk[4 * kk + 3], laneA);
        uint32_t l1b = (uint32_t)__shfl((int)pk[4 * kk + 2], laneB);
        uint32_t h1b = (uint32_t)__shfl((int)pk[4 * kk + 3], laneB);
        u32x4 wvv = { hiSel ? l1  : l0,  hiSel ? h1  : h0,
                      hiSel ? l1b : l0b, hiSel ? h1b : h0b };
        bf16x8 pa = __builtin_bit_cast(bf16x8, wvv);
        __builtin_amdgcn_s_setprio(1);
#pragma unroll
        for (int jd = 0; jd < 4; jd++) {
            bf16x8 bv = *(const bf16x8*)&Vt[(jd * 16 + c) * 200 + kt * 32 + quad * 8];
            acc2[jd] = MFMA_BF16(pa, bv, acc2[jd]);
        }
        __builtin_amdgcn_s_setprio(0);
    }

    // ---- store O rows of this F (sink factor already folded into P)
#pragma unroll
    for (int jd = 0; jd < 4; jd++)
#pragma unroll
        for (int r = 0; r < 4; r++)
            q[(size_t)(i0 + F * 16 + quad * 4 + r) * 4096 + h * 64 + jd * 16 + c]
                = (__bf16)acc2[jd][r];
}

// ---------------------------------------------------------------------------
// Attention, fused RoPE, in-place on q. Grid (32 q-tiles, 8 kv-heads),
// 512 threads = 8 waves; wave w = head kvh*8+w, all 64 rows of the tile.
// K (rope'd) and V^T staged ONCE per block (shared by 8 heads).
// LDS: Ks[192][72] (2-way bank), Vt[64][200] (2-way bank) = 53KB.
// ---------------------------------------------------------------------------
__global__ __launch_bounds__(512) void attn_kernel(
    __bf16* __restrict__ q, const __bf16* __restrict__ k,
    const __bf16* __restrict__ v, const float* __restrict__ sinks,
    const float* __restrict__ rope)
{
    __shared__ __align__(16) __bf16 Ks[192 * 72];
    __shared__ __align__(16) __bf16 Vt[64 * 200];

    const int tid = threadIdx.x, lane = tid & 63, w = tid >> 6;
    const int quad = lane >> 4, c = lane & 15;
    const int i0  = blockIdx.x * 64;
    const int kvh = blockIdx.y;
    const int h   = kvh * 8 + w;
    const int k0  = i0 - 128;
    const float scale = 0.16832169878499658f;   // (0.1*ln32+1)/sqrt(64)

    // ---- stage K with rope: 192 rows x 64 dims, 768 units of 16 elems
#pragma unroll
    for (int it = 0; it < 2; it++) {
        int unit = it * 512 + tid;
        if (unit < 768) {
            int krow = unit >> 2;
            int kdg  = (unit & 3) * 8;
            int j = k0 + krow; if (j < 0) j = 0;
            const __bf16* gp = k + (size_t)j * 512 + kvh * 64 + kdg;
            bf16x8 x1 = *(const bf16x8*)(gp);
            bf16x8 x2 = *(const bf16x8*)(gp + 32);
            const float* rc = rope + (size_t)j * 128 + kdg;
            bf16x8 o1, o2;
#pragma unroll
            for (int t = 0; t < 8; t++) {
                float cc = rc[t], si = rc[64 + t];
                float a = (float)x1[t], b = (float)x2[t];
                o1[t] = (__bf16)(a * cc - b * si);
                o2[t] = (__bf16)(b * cc + a * si);
            }
            *(bf16x8*)&Ks[krow * 72 + kdg]      = o1;
            *(bf16x8*)&Ks[krow * 72 + kdg + 32] = o2;
        }
    }

    // ---- stage V transposed: Vt[d][s]  (s = staged key index)
    {
        const int vrow = tid & 63;
        const int d0   = (tid >> 6) * 8;
#pragma unroll
        for (int it = 0; it < 3; it++) {
            int s = it * 64 + vrow;
            int j = k0 + s; if (j < 0) j = 0;
            bf16x8 t = *(const bf16x8*)(v + (size_t)j * 512 + kvh * 64 + d0);
#pragma unroll
            for (int u = 0; u < 8; u++) Vt[(d0 + u) * 200 + s] = t[u];
        }
    }

    // ---- Q fragments (B-operand layout: row=c), rope + scale folded in
    bf16x8 qf[4][2];
#pragma unroll
    for (int f = 0; f < 4; f++) {
        const int row = i0 + f * 16 + c;
        const __bf16* gp = q + (size_t)row * 4096 + h * 64 + quad * 8;
        bf16x8 x1 = *(const bf16x8*)(gp);
        bf16x8 x2 = *(const bf16x8*)(gp + 32);
        const float* rc = rope + (size_t)row * 128 + quad * 8;
        bf16x8 o1, o2;
#pragma unroll
        for (int t = 0; t < 8; t++) {
            float cc = rc[t] * scale, si = rc[64 + t] * scale;
            float a = (float)x1[t], b = (float)x2[t];
            o1[t] = (__bf16)(a * cc - b * si);
            o2[t] = (__bf16)(b * cc + a * si);
        }
        qf[f][0] = o1; qf[f][1] = o2;
    }

    __syncthreads();

    const float sk   = sinks[h];
    const int laneA  = ((quad & 1) << 5) + c;   // owner quad (quad&1)*2
    const int laneB  = laneA + 16;              // owner quad (quad&1)*2+1
    const bool hiSel = (quad >> 1) != 0;        // needs j = 2kt+1
    const int db     = 128 + c - quad * 4;      // ig - jg, jj/r part removed

    attn_f_step<0>(Ks, Vt, q, qf[0][0], qf[0][1], i0, h, k0, sk, c, quad, laneA, laneB, hiSel, db);
    attn_f_step<1>(Ks, Vt, q, qf[1][0], qf[1][1], i0, h, k0, sk, c, quad, laneA, laneB, hiSel, db);
    attn_f_step<2>(Ks, Vt, q, qf[2][0], qf[2][1], i0, h, k0, sk, c, quad, laneA, laneB, hiSel, db);
    attn_f_step<3>(Ks, Vt, q, qf[3][0], qf[3][1], i0, h, k0, sk, c, quad, laneA, laneB, hiSel, db);
}

// ---------------------------------------------------------------------------
extern "C" void kernel_launch(void* const* d_in, const int* in_sizes, int n_in,
                              void* d_out, int out_size, void* d_ws, size_t ws_size,
                              hipStream_t stream) {
    const float* x    = (const float*)d_in[0];
    const float* rope = (const float*)d_in[1];
    const float* wq   = (const float*)d_in[2];
    const float* bq   = (const float*)d_in[3];
    const float* wk   = (const float*)d_in[4];
    const float* bk   = (const float*)d_in[5];
    const float* wv   = (const float*)d_in[6];
    const float* bv   = (const float*)d_in[7];
    const float* wo   = (const float*)d_in[8];
    const float* bo   = (const float*)d_in[9];
    const float* sk   = (const float*)d_in[10];
    float* out = (float*)d_out;

    __bf16* wsb = (__bf16*)d_ws;
    __bf16* xb  = wsb + XB;
    __bf16* wqb = wsb + WQB;
    __bf16* wkb = wsb + WKB;
    __bf16* wvb = wsb + WVB;
    __bf16* wob = wsb + WOB;
    __bf16* qb  = wsb + QB;
    __bf16* kb  = wsb + KB;
    __bf16* vb  = wsb + VB;
    __bf16* po0 = wsb + 0L;            // oproj partials overlay dead xb/wqb
    __bf16* po1 = wsb + 5898240L;

    convert_kernel<<<15840, 256, 0, stream>>>(x, wq, wk, wv, wo, xb);
    qkv_kernel<<<dim3(16, 40), 256, 0, stream>>>(xb, wqb, bq, wkb, bk, wvb, bv,
                                                 qb, kb, vb);
    attn_kernel<<<dim3(32, 8), 512, 0, stream>>>(qb, kb, vb, sk, rope);
    oproj_kernel<<<dim3(16, 23, 2), 256, 0, stream>>>(qb, wob, po0, po1);
    reduce_kernel<<<2880, 256, 0, stream>>>(po0, po1, bo, out);
}